// Round 8
// baseline (18751.237 us; speedup 1.0000x reference)
//
#include <hip/hip_runtime.h>
#include <hip/hip_fp16.h>
#include <math.h>

// Problem dims (fixed by reference)
//  B=1024, T=128, I=128, H=256, 3H=768, K=8, E1=512, E2=256, C=2

struct __align__(8)  Half4 { _Float16 x, y, z, w; };
struct __align__(16) Half8 { _Float16 h[8]; };

// ---------------------------------------------------------------------------
// fp32 GEMM, 128x128 tile, 256 threads, 8x8 per-thread microtile.
// ---------------------------------------------------------------------------
template<int ACT>
__global__ __launch_bounds__(256)
void gemm_f32(const float* __restrict__ A, const float* __restrict__ W,
              const float* __restrict__ bias, float* __restrict__ C,
              int K,
              long a_sT, long a_sB, long a_sZ,
              long w_sZ, long b_sZ, long c_row, long c_sZ)
{
  __shared__ alignas(16) float As[16][132];
  __shared__ alignas(16) float Ws[16][132];
  const int z = blockIdx.z;
  const float* Az = A + (long)z * a_sZ;
  const float* Wz = W + (long)z * w_sZ;
  const float* bz = bias + (long)z * b_sZ;
  const int m0 = blockIdx.y * 128;
  const int n0 = blockIdx.x * 128;
  const int tid = threadIdx.x;
  const int tx = tid & 15, ty = tid >> 4;

  const int row0 = tid >> 2, kq0 = tid & 3;
  const int row1 = (tid + 256) >> 2, kq1 = kq0;

  float acc[8][8];
  #pragma unroll
  for (int i = 0; i < 8; ++i)
    #pragma unroll
    for (int j = 0; j < 8; ++j) acc[i][j] = 0.f;

  const int ma0 = m0 + row0, ma1 = m0 + row1;
  const float* apr0 = Az + (long)(ma0 >> 10) * a_sT + (long)(ma0 & 1023) * a_sB + kq0 * 4;
  const float* apr1 = Az + (long)(ma1 >> 10) * a_sT + (long)(ma1 & 1023) * a_sB + kq1 * 4;
  const float* wpr0 = Wz + (long)(n0 + row0) * K + kq0 * 4;
  const float* wpr1 = Wz + (long)(n0 + row1) * K + kq1 * 4;

  float4 pa0 = *(const float4*)(apr0);
  float4 pa1 = *(const float4*)(apr1);
  float4 pw0 = *(const float4*)(wpr0);
  float4 pw1 = *(const float4*)(wpr1);

  for (int k0 = 0; k0 < K; k0 += 16) {
    As[kq0*4+0][row0] = pa0.x; As[kq0*4+1][row0] = pa0.y;
    As[kq0*4+2][row0] = pa0.z; As[kq0*4+3][row0] = pa0.w;
    As[kq1*4+0][row1] = pa1.x; As[kq1*4+1][row1] = pa1.y;
    As[kq1*4+2][row1] = pa1.z; As[kq1*4+3][row1] = pa1.w;
    Ws[kq0*4+0][row0] = pw0.x; Ws[kq0*4+1][row0] = pw0.y;
    Ws[kq0*4+2][row0] = pw0.z; Ws[kq0*4+3][row0] = pw0.w;
    Ws[kq1*4+0][row1] = pw1.x; Ws[kq1*4+1][row1] = pw1.y;
    Ws[kq1*4+2][row1] = pw1.z; Ws[kq1*4+3][row1] = pw1.w;
    __syncthreads();

    if (k0 + 16 < K) {
      pa0 = *(const float4*)(apr0 + k0 + 16);
      pa1 = *(const float4*)(apr1 + k0 + 16);
      pw0 = *(const float4*)(wpr0 + k0 + 16);
      pw1 = *(const float4*)(wpr1 + k0 + 16);
    }

    #pragma unroll
    for (int kk = 0; kk < 16; ++kk) {
      float4 a0 = *(const float4*)&As[kk][ty * 8];
      float4 a1 = *(const float4*)&As[kk][ty * 8 + 4];
      float4 b0 = *(const float4*)&Ws[kk][tx * 4];
      float4 b1 = *(const float4*)&Ws[kk][64 + tx * 4];
      float a[8] = {a0.x,a0.y,a0.z,a0.w,a1.x,a1.y,a1.z,a1.w};
      float b[8] = {b0.x,b0.y,b0.z,b0.w,b1.x,b1.y,b1.z,b1.w};
      #pragma unroll
      for (int i = 0; i < 8; ++i)
        #pragma unroll
        for (int j = 0; j < 8; ++j)
          acc[i][j] = fmaf(a[i], b[j], acc[i][j]);
    }
    __syncthreads();
  }

  float4 bv0 = *(const float4*)&bz[n0 + tx * 4];
  float4 bv1 = *(const float4*)&bz[n0 + 64 + tx * 4];
  #pragma unroll
  for (int i = 0; i < 8; ++i) {
    int m = m0 + ty * 8 + i;
    float* cp = C + (long)m * c_row + (long)z * c_sZ + n0;
    float4 o0, o1;
    o0.x = acc[i][0] + bv0.x; o0.y = acc[i][1] + bv0.y;
    o0.z = acc[i][2] + bv0.z; o0.w = acc[i][3] + bv0.w;
    o1.x = acc[i][4] + bv1.x; o1.y = acc[i][5] + bv1.y;
    o1.z = acc[i][6] + bv1.z; o1.w = acc[i][7] + bv1.w;
    if (ACT == 1) {
      o0.x = fmaxf(o0.x, 0.f); o0.y = fmaxf(o0.y, 0.f);
      o0.z = fmaxf(o0.z, 0.f); o0.w = fmaxf(o0.w, 0.f);
      o1.x = fmaxf(o1.x, 0.f); o1.y = fmaxf(o1.y, 0.f);
      o1.z = fmaxf(o1.z, 0.f); o1.w = fmaxf(o1.w, 0.f);
    }
    *(float4*)(cp + tx * 4) = o0;
    *(float4*)(cp + 64 + tx * 4) = o1;
  }
}

// ---------------------------------------------------------------------------
// One-time W_hh transpose + f16 convert into coalesced-by-d layout:
//   Wt[(k4*3 + gate)*256 + d] = Half4{ W[gate*256+d][4k4 .. 4k4+3] }
// ---------------------------------------------------------------------------
__global__ __launch_bounds__(64)
void transpose_whh(const float* __restrict__ W, Half4* __restrict__ Wt)
{
  const int row = blockIdx.x;          // 0..767 = gate*256 + d
  const int k4 = threadIdx.x;          // 0..63
  const int g = row >> 8, d = row & 255;
  float4 v = *(const float4*)(W + (long)row * 256 + k4 * 4);
  Half4 h;
  h.x = (_Float16)v.x; h.y = (_Float16)v.y;
  h.z = (_Float16)v.z; h.w = (_Float16)v.w;
  Wt[((long)k4 * 3 + g) * 256 + d] = h;
}

// ---------------------------------------------------------------------------
// GRU recurrence, 8-way split-K x 2-d-per-thread. 256 blocks x 1024 threads;
// block = 4 batch rows, 16 waves/CU.
// k-loop thread (dp = tid&127, e = tid>>7): owns output dims d0=2dp, 2dp+1
// and k-range [32e, 32e+32) (8 k4 iters). Per k4: one 16B Half8 W load per
// gate (perfectly coalesced 1KB/wave), 4 LDS float4 h reads (broadcast),
// 96 fmaf. LDS read instrs HALVED vs the 4-way/1-d layout (32 vs 64 b128
// per thread-step) -- that pipe was the measured floor.
// Epilogue thread maps to (row = e>>1, d = dp + (e&1)*128): reduces 8
// partials x 3 gates, applies activations, updates h. Partials in LDS
// [8][12][256] = 96 KB; +hs 4KB -> 100 KB, 1 block/CU.
// ---------------------------------------------------------------------------
__global__ __launch_bounds__(1024, 4)
void gru_rec(const float* __restrict__ gi, const Half4* __restrict__ Wt,
             const float* __restrict__ b_hh, float* __restrict__ h_state,
             float* __restrict__ h_out, int Tc, int store_all)
{
  __shared__ alignas(16) float hs[4][256];
  __shared__ alignas(16) float part[8][12][256];   // 96 KB
  const int tid = threadIdx.x;
  const int dp = tid & 127;
  const int e  = tid >> 7;              // 0..7: k-eighth
  const int b0 = blockIdx.x * 4;
  // epilogue identity: row erow, hidden dim ed (coalesced in dp)
  const int erow = e >> 1;
  const int ed   = dp + (e & 1) * 128;
  hs[erow][ed] = h_state[(long)(b0 + erow) * 256 + ed];
  __syncthreads();

  const float bhr = b_hh[ed];
  const float bhz = b_hh[256 + ed];
  const float bhn = b_hh[512 + ed];
  const int d0 = dp * 2;                // k-loop identity: dims d0, d0+1
  const int k4lo = e * 8;

  for (int t = 0; t < Tc; ++t) {
    // epilogue gi loads up front (nontemporal single-use stream);
    // latency overlaps the whole k-loop
    const float* gip = gi + ((long)t * 1024 + b0 + erow) * 768;
    const float gir = __builtin_nontemporal_load(gip + ed);
    const float giz = __builtin_nontemporal_load(gip + 256 + ed);
    const float gin = __builtin_nontemporal_load(gip + 512 + ed);

    float acc[3][4][2];
    #pragma unroll
    for (int g = 0; g < 3; ++g)
      #pragma unroll
      for (int r = 0; r < 4; ++r) { acc[g][r][0] = 0.f; acc[g][r][1] = 0.f; }

    #pragma unroll
    for (int k4i = 0; k4i < 8; ++k4i) {
      const int k4 = k4lo + k4i;
      float4 hv[4];
      #pragma unroll
      for (int r = 0; r < 4; ++r)
        hv[r] = *(const float4*)&hs[r][k4 * 4];   // LDS broadcast
      #pragma unroll
      for (int g = 0; g < 3; ++g) {
        Half8 w8 = *(const Half8*)(Wt + (long)(k4 * 3 + g) * 256 + d0);
        const float w0 = (float)w8.h[0], w1 = (float)w8.h[1],
                    w2 = (float)w8.h[2], w3 = (float)w8.h[3];
        const float v0 = (float)w8.h[4], v1 = (float)w8.h[5],
                    v2 = (float)w8.h[6], v3 = (float)w8.h[7];
        #pragma unroll
        for (int r = 0; r < 4; ++r) {
          float a0 = acc[g][r][0], a1 = acc[g][r][1];
          a0 = fmaf(hv[r].x, w0, a0); a0 = fmaf(hv[r].y, w1, a0);
          a0 = fmaf(hv[r].z, w2, a0); a0 = fmaf(hv[r].w, w3, a0);
          a1 = fmaf(hv[r].x, v0, a1); a1 = fmaf(hv[r].y, v1, a1);
          a1 = fmaf(hv[r].z, v2, a1); a1 = fmaf(hv[r].w, v3, a1);
          acc[g][r][0] = a0; acc[g][r][1] = a1;
        }
      }
    }
    #pragma unroll
    for (int g = 0; g < 3; ++g)
      #pragma unroll
      for (int r = 0; r < 4; ++r)
        *(float2*)&part[e][g * 4 + r][d0] =
            make_float2(acc[g][r][0], acc[g][r][1]);
    __syncthreads();   // partials visible; all eighths done reading hs

    // reduce 8 partials for (erow, ed), activate, update h
    {
      float sr = 0.f, sz = 0.f, sn = 0.f;
      #pragma unroll
      for (int ee = 0; ee < 8; ++ee) {
        sr += part[ee][0 * 4 + erow][ed];
        sz += part[ee][1 * 4 + erow][ed];
        sn += part[ee][2 * 4 + erow][ed];
      }
      float rg = 1.f / (1.f + __expf(-(gir + sr + bhr)));
      float zg = 1.f / (1.f + __expf(-(giz + sz + bhz)));
      float ng = tanhf(gin + rg * (sn + bhn));
      float hn = (1.f - zg) * ng + zg * hs[erow][ed];
      hs[erow][ed] = hn;   // unique owner of (erow, ed)
      if (store_all)
        h_out[((long)t * 1024 + b0 + erow) * 256 + ed] = hn;
    }
    __syncthreads();   // new h visible for step t+1
  }
  h_state[(long)(b0 + erow) * 256 + ed] = hs[erow][ed];
}

// ---------------------------------------------------------------------------
// Soft cluster assignment: q[b,k] ∝ 1/(1+||z_b - c_k||²)  (alpha=1), normalized.
// ---------------------------------------------------------------------------
__global__ __launch_bounds__(64)
void cluster_q(const float* __restrict__ zlat, const float* __restrict__ centers,
               float* __restrict__ q)
{
  __shared__ float red[64];
  __shared__ float qv[8];
  const int b = blockIdx.x;
  const int tid = threadIdx.x;
  const int k = tid >> 3, p = tid & 7;
  const float4* zp = (const float4*)(zlat + (long)b * 256 + p * 32);
  const float4* cp = (const float4*)(centers + (long)k * 256 + p * 32);
  float s = 0.f;
  #pragma unroll
  for (int i = 0; i < 8; ++i) {
    float4 zv = zp[i], cv = cp[i];
    float dx = zv.x - cv.x, dy = zv.y - cv.y;
    float dz = zv.z - cv.z, dw = zv.w - cv.w;
    s += dx*dx + dy*dy + dz*dz + dw*dw;
  }
  red[tid] = s;
  __syncthreads();
  if (tid < 8) {
    float d2 = 0.f;
    #pragma unroll
    for (int p2 = 0; p2 < 8; ++p2) d2 += red[tid * 8 + p2];
    qv[tid] = 1.f / (1.f + d2);
  }
  __syncthreads();
  if (tid < 8) {
    float ssum = 0.f;
    #pragma unroll
    for (int kk = 0; kk < 8; ++kk) ssum += qv[kk];
    q[(long)b * 8 + tid] = qv[tid] / ssum;
  }
}

// ---------------------------------------------------------------------------
// logits[b,k,c] = h2[b,k,:]·eW3[k,c,:] + eb3[k,c]; preds[b,c] = Σ_k q[b,k]*logits
// ---------------------------------------------------------------------------
__global__ __launch_bounds__(256)
void combine_preds(const float* __restrict__ h2, const float* __restrict__ eW3,
                   const float* __restrict__ eb3, const float* __restrict__ q,
                   float* __restrict__ out)
{
  __shared__ float p0[256], p1[256];
  __shared__ float lc[16];
  const int b = blockIdx.x;
  const int tid = threadIdx.x;
  const int k = tid >> 5, w = tid & 31;
  const float* h2p = h2 + (long)b * (8 * 256) + (long)k * 256 + w * 8;
  const float* w0  = eW3 + (long)k * 512 + w * 8;          // c=0
  const float* w1  = eW3 + (long)k * 512 + 256 + w * 8;    // c=1
  float c0 = 0.f, c1 = 0.f;
  #pragma unroll
  for (int i = 0; i < 8; ++i) {
    float hv = h2p[i];
    c0 = fmaf(hv, w0[i], c0);
    c1 = fmaf(hv, w1[i], c1);
  }
  p0[tid] = c0; p1[tid] = c1;
  __syncthreads();
  if (tid < 16) {
    int kk = tid >> 1, c = tid & 1;
    const float* pp = (c == 0) ? p0 : p1;
    float s = 0.f;
    for (int w2 = 0; w2 < 32; ++w2) s += pp[kk * 32 + w2];
    s += eb3[kk * 2 + c];
    lc[tid] = q[(long)b * 8 + kk] * s;
  }
  __syncthreads();
  if (tid < 2) {
    float s = 0.f;
    #pragma unroll
    for (int kk = 0; kk < 8; ++kk) s += lc[kk * 2 + tid];
    out[(long)b * 2 + tid] = s;
  }
}

// Zero-fill helper (avoid relying on memset semantics under graph capture)
__global__ __launch_bounds__(256)
void zero_fill(float* __restrict__ p, long n)
{
  long i = (long)blockIdx.x * 256 + threadIdx.x;
  if (i < n) p[i] = 0.f;
}

// ---------------------------------------------------------------------------
extern "C" void kernel_launch(void* const* d_in, const int* in_sizes, int n_in,
                              void* d_out, int out_size, void* d_ws, size_t ws_size,
                              hipStream_t stream)
{
  const float* x       = (const float*)d_in[0];
  const float* W_ih0   = (const float*)d_in[1];
  const float* W_hh0   = (const float*)d_in[2];
  const float* b_ih0   = (const float*)d_in[3];
  const float* b_hh0   = (const float*)d_in[4];
  const float* W_ih1   = (const float*)d_in[5];
  const float* W_hh1   = (const float*)d_in[6];
  const float* b_ih1   = (const float*)d_in[7];
  const float* b_hh1   = (const float*)d_in[8];
  const float* centers = (const float*)d_in[9];
  const float* eW1     = (const float*)d_in[10];
  const float* eb1     = (const float*)d_in[11];
  const float* eW2     = (const float*)d_in[12];
  const float* eb2     = (const float*)d_in[13];
  const float* eW3     = (const float*)d_in[14];
  const float* eb3     = (const float*)d_in[15];
  float* out = (float*)d_out;
  (void)in_sizes; (void)n_in; (void)out_size;

  // ---- workspace layout ----
  char* base = (char*)d_ws;
  size_t off = 0;
  auto alloc = [&](size_t nbytes) -> void* {
    void* p = base + off;
    off += (nbytes + 255) & ~(size_t)255;
    return p;
  };
  float* h0_state = (float*)alloc(1024ull * 256 * 4);
  float* h1_state = (float*)alloc(1024ull * 256 * 4);   // == z after layer 1
  float* qbuf     = (float*)alloc(1024ull * 8 * 4);
  float* h1buf    = (float*)alloc(1024ull * 8 * 512 * 4);
  float* h2buf    = (float*)alloc(1024ull * 8 * 256 * 4);
  Half4* Wt0      = (Half4*)alloc(768ull * 256 * 2);    // f16 transposed W_hh0
  Half4* Wt1      = (Half4*)alloc(768ull * 256 * 2);    // f16 transposed W_hh1
  const size_t fixed = off;

  // largest T-chunk that fits ws_size (deterministic given ws_size)
  int Tc = 2;
  const int cands[7] = {128, 64, 32, 16, 8, 4, 2};
  for (int ci = 0; ci < 7; ++ci) {
    size_t need = fixed + (size_t)cands[ci] * 1024 * (768 + 768 + 256) * 4 + 1024;
    if (need <= ws_size) { Tc = cands[ci]; break; }
  }
  float* gi0 = (float*)alloc((size_t)Tc * 1024 * 768 * 4);
  float* gi1 = (float*)alloc((size_t)Tc * 1024 * 768 * 4);
  float* h0c = (float*)alloc((size_t)Tc * 1024 * 256 * 4);

  // ---- zero recurrent states; transpose W_hh (once per call) ----
  {
    long n = 2L * 1024 * 256;   // h0_state + h1_state are contiguous
    zero_fill<<<dim3((unsigned)((n + 255) / 256)), 256, 0, stream>>>(h0_state, n);
    transpose_whh<<<768, 64, 0, stream>>>(W_hh0, Wt0);
    transpose_whh<<<768, 64, 0, stream>>>(W_hh1, Wt1);
  }

  // ---- 2-layer GRU, serial chunks (dual-stream pipelining thrashes L3) ----
  for (int t0 = 0; t0 < 128; t0 += Tc) {
    // gi0[tl,b,:] = x[b, t0+tl, :] @ W_ih0^T + b_ih0
    gemm_f32<0><<<dim3(6, Tc * 8, 1), 256, 0, stream>>>(
        x + (long)t0 * 128, W_ih0, b_ih0, gi0, 128,
        /*a_sT*/ 128, /*a_sB*/ 128L * 128, /*a_sZ*/ 0,
        /*w_sZ*/ 0, /*b_sZ*/ 0, /*c_row*/ 768, /*c_sZ*/ 0);
    gru_rec<<<256, 1024, 0, stream>>>(gi0, Wt0, b_hh0, h0_state, h0c, Tc, 1);

    // gi1[tl,b,:] = h0c[tl,b,:] @ W_ih1^T + b_ih1
    gemm_f32<0><<<dim3(6, Tc * 8, 1), 256, 0, stream>>>(
        h0c, W_ih1, b_ih1, gi1, 256,
        /*a_sT*/ 1024L * 256, /*a_sB*/ 256, /*a_sZ*/ 0,
        /*w_sZ*/ 0, /*b_sZ*/ 0, /*c_row*/ 768, /*c_sZ*/ 0);
    gru_rec<<<256, 1024, 0, stream>>>(gi1, Wt1, b_hh1, h1_state, nullptr, Tc, 0);
  }

  // ---- soft cluster assignment ----
  cluster_q<<<1024, 64, 0, stream>>>(h1_state, centers, qbuf);

  // ---- experts: h1 = relu(z @ eW1[k]^T + eb1[k]) ----
  gemm_f32<1><<<dim3(4, 8, 8), 256, 0, stream>>>(
      h1_state, eW1, eb1, h1buf, 256,
      /*a_sT*/ 0, /*a_sB*/ 256, /*a_sZ*/ 0,
      /*w_sZ*/ 512L * 256, /*b_sZ*/ 512, /*c_row*/ 8L * 512, /*c_sZ*/ 512);
  // h2 = relu(h1 @ eW2[k]^T + eb2[k])
  gemm_f32<1><<<dim3(2, 8, 8), 256, 0, stream>>>(
      h1buf, eW2, eb2, h2buf, 512,
      /*a_sT*/ 0, /*a_sB*/ 8L * 512, /*a_sZ*/ 512,
      /*w_sZ*/ 256L * 512, /*b_sZ*/ 256, /*c_row*/ 8L * 256, /*c_sZ*/ 256);

  // ---- logits + q-weighted combine ----
  combine_preds<<<1024, 256, 0, stream>>>(h2buf, eW3, eb3, qbuf, out);
}

// Round 9
// 18049.773 us; speedup vs baseline: 1.0389x; 1.0389x over previous
//
#include <hip/hip_runtime.h>
#include <hip/hip_fp16.h>
#include <math.h>

// Problem dims (fixed by reference)
//  B=1024, T=128, I=128, H=256, 3H=768, K=8, E1=512, E2=256, C=2

struct __align__(8)  Half4 { _Float16 x, y, z, w; };
struct __align__(16) Half8 { _Float16 h[8]; };

// ---------------------------------------------------------------------------
// fp32 GEMM, 128x128 tile, 256 threads, 8x8 per-thread microtile.
// ---------------------------------------------------------------------------
template<int ACT>
__global__ __launch_bounds__(256)
void gemm_f32(const float* __restrict__ A, const float* __restrict__ W,
              const float* __restrict__ bias, float* __restrict__ C,
              int K,
              long a_sT, long a_sB, long a_sZ,
              long w_sZ, long b_sZ, long c_row, long c_sZ)
{
  __shared__ alignas(16) float As[16][132];
  __shared__ alignas(16) float Ws[16][132];
  const int z = blockIdx.z;
  const float* Az = A + (long)z * a_sZ;
  const float* Wz = W + (long)z * w_sZ;
  const float* bz = bias + (long)z * b_sZ;
  const int m0 = blockIdx.y * 128;
  const int n0 = blockIdx.x * 128;
  const int tid = threadIdx.x;
  const int tx = tid & 15, ty = tid >> 4;

  const int row0 = tid >> 2, kq0 = tid & 3;
  const int row1 = (tid + 256) >> 2, kq1 = kq0;

  float acc[8][8];
  #pragma unroll
  for (int i = 0; i < 8; ++i)
    #pragma unroll
    for (int j = 0; j < 8; ++j) acc[i][j] = 0.f;

  const int ma0 = m0 + row0, ma1 = m0 + row1;
  const float* apr0 = Az + (long)(ma0 >> 10) * a_sT + (long)(ma0 & 1023) * a_sB + kq0 * 4;
  const float* apr1 = Az + (long)(ma1 >> 10) * a_sT + (long)(ma1 & 1023) * a_sB + kq1 * 4;
  const float* wpr0 = Wz + (long)(n0 + row0) * K + kq0 * 4;
  const float* wpr1 = Wz + (long)(n0 + row1) * K + kq1 * 4;

  float4 pa0 = *(const float4*)(apr0);
  float4 pa1 = *(const float4*)(apr1);
  float4 pw0 = *(const float4*)(wpr0);
  float4 pw1 = *(const float4*)(wpr1);

  for (int k0 = 0; k0 < K; k0 += 16) {
    As[kq0*4+0][row0] = pa0.x; As[kq0*4+1][row0] = pa0.y;
    As[kq0*4+2][row0] = pa0.z; As[kq0*4+3][row0] = pa0.w;
    As[kq1*4+0][row1] = pa1.x; As[kq1*4+1][row1] = pa1.y;
    As[kq1*4+2][row1] = pa1.z; As[kq1*4+3][row1] = pa1.w;
    Ws[kq0*4+0][row0] = pw0.x; Ws[kq0*4+1][row0] = pw0.y;
    Ws[kq0*4+2][row0] = pw0.z; Ws[kq0*4+3][row0] = pw0.w;
    Ws[kq1*4+0][row1] = pw1.x; Ws[kq1*4+1][row1] = pw1.y;
    Ws[kq1*4+2][row1] = pw1.z; Ws[kq1*4+3][row1] = pw1.w;
    __syncthreads();

    if (k0 + 16 < K) {
      pa0 = *(const float4*)(apr0 + k0 + 16);
      pa1 = *(const float4*)(apr1 + k0 + 16);
      pw0 = *(const float4*)(wpr0 + k0 + 16);
      pw1 = *(const float4*)(wpr1 + k0 + 16);
    }

    #pragma unroll
    for (int kk = 0; kk < 16; ++kk) {
      float4 a0 = *(const float4*)&As[kk][ty * 8];
      float4 a1 = *(const float4*)&As[kk][ty * 8 + 4];
      float4 b0 = *(const float4*)&Ws[kk][tx * 4];
      float4 b1 = *(const float4*)&Ws[kk][64 + tx * 4];
      float a[8] = {a0.x,a0.y,a0.z,a0.w,a1.x,a1.y,a1.z,a1.w};
      float b[8] = {b0.x,b0.y,b0.z,b0.w,b1.x,b1.y,b1.z,b1.w};
      #pragma unroll
      for (int i = 0; i < 8; ++i)
        #pragma unroll
        for (int j = 0; j < 8; ++j)
          acc[i][j] = fmaf(a[i], b[j], acc[i][j]);
    }
    __syncthreads();
  }

  float4 bv0 = *(const float4*)&bz[n0 + tx * 4];
  float4 bv1 = *(const float4*)&bz[n0 + 64 + tx * 4];
  #pragma unroll
  for (int i = 0; i < 8; ++i) {
    int m = m0 + ty * 8 + i;
    float* cp = C + (long)m * c_row + (long)z * c_sZ + n0;
    float4 o0, o1;
    o0.x = acc[i][0] + bv0.x; o0.y = acc[i][1] + bv0.y;
    o0.z = acc[i][2] + bv0.z; o0.w = acc[i][3] + bv0.w;
    o1.x = acc[i][4] + bv1.x; o1.y = acc[i][5] + bv1.y;
    o1.z = acc[i][6] + bv1.z; o1.w = acc[i][7] + bv1.w;
    if (ACT == 1) {
      o0.x = fmaxf(o0.x, 0.f); o0.y = fmaxf(o0.y, 0.f);
      o0.z = fmaxf(o0.z, 0.f); o0.w = fmaxf(o0.w, 0.f);
      o1.x = fmaxf(o1.x, 0.f); o1.y = fmaxf(o1.y, 0.f);
      o1.z = fmaxf(o1.z, 0.f); o1.w = fmaxf(o1.w, 0.f);
    }
    *(float4*)(cp + tx * 4) = o0;
    *(float4*)(cp + 64 + tx * 4) = o1;
  }
}

// ---------------------------------------------------------------------------
// One-time W_hh transpose + f16 convert into coalesced-by-d layout:
//   Wt[(k4*3 + gate)*256 + d] = Half4{ W[gate*256+d][4k4 .. 4k4+3] }
// ---------------------------------------------------------------------------
__global__ __launch_bounds__(64)
void transpose_whh(const float* __restrict__ W, Half4* __restrict__ Wt)
{
  const int row = blockIdx.x;          // 0..767 = gate*256 + d
  const int k4 = threadIdx.x;          // 0..63
  const int g = row >> 8, d = row & 255;
  float4 v = *(const float4*)(W + (long)row * 256 + k4 * 4);
  Half4 h;
  h.x = (_Float16)v.x; h.y = (_Float16)v.y;
  h.z = (_Float16)v.z; h.w = (_Float16)v.w;
  Wt[((long)k4 * 3 + g) * 256 + d] = h;
}

// ---------------------------------------------------------------------------
// GRU recurrence, 8-way split-K x 2-d-per-thread. 256 blocks x 1024 threads;
// block = 4 batch rows, 16 waves/CU.
// NOTE: __launch_bounds__(1024) with NO second arg. Round-8's (1024, 4)
// capped the allocator at 64 VGPR -> scratch spill -> 5.6 GB HBM fetch and
// VALUBusy 6%. Plain (1024) permits up to 128 VGPR (16 waves/CU is the HW
// floor for 1024-thread blocks); this kernel needs ~80.
// k-loop thread (dp = tid&127, e = tid>>7): owns output dims d0=2dp, 2dp+1
// and k-range [32e, 32e+32) (8 k4 iters). Per k4: one 16B Half8 W load per
// gate (coalesced 1KB/wave), 4 LDS float4 h reads (broadcast), 96 fmaf.
// LDS read instrs HALVED vs the 4-way/1-d layout -- the measured floor.
// Epilogue thread (row = e>>1, d = dp + (e&1)*128): reduces 8 partials x 3
// gates, activations, h update. LDS: part 96 KB + hs 4 KB, 1 block/CU.
// ---------------------------------------------------------------------------
__global__ __launch_bounds__(1024)
void gru_rec(const float* __restrict__ gi, const Half4* __restrict__ Wt,
             const float* __restrict__ b_hh, float* __restrict__ h_state,
             float* __restrict__ h_out, int Tc, int store_all)
{
  __shared__ alignas(16) float hs[4][256];
  __shared__ alignas(16) float part[8][12][256];   // 96 KB
  const int tid = threadIdx.x;
  const int dp = tid & 127;
  const int e  = tid >> 7;              // 0..7: k-eighth
  const int b0 = blockIdx.x * 4;
  // epilogue identity: row erow, hidden dim ed (coalesced in dp)
  const int erow = e >> 1;
  const int ed   = dp + (e & 1) * 128;
  hs[erow][ed] = h_state[(long)(b0 + erow) * 256 + ed];
  __syncthreads();

  const float bhr = b_hh[ed];
  const float bhz = b_hh[256 + ed];
  const float bhn = b_hh[512 + ed];
  const int d0 = dp * 2;                // k-loop identity: dims d0, d0+1
  const int k4lo = e * 8;

  for (int t = 0; t < Tc; ++t) {
    // epilogue gi loads up front (nontemporal single-use stream);
    // latency overlaps the whole k-loop
    const float* gip = gi + ((long)t * 1024 + b0 + erow) * 768;
    const float gir = __builtin_nontemporal_load(gip + ed);
    const float giz = __builtin_nontemporal_load(gip + 256 + ed);
    const float gin = __builtin_nontemporal_load(gip + 512 + ed);

    float acc[3][4][2];
    #pragma unroll
    for (int g = 0; g < 3; ++g)
      #pragma unroll
      for (int r = 0; r < 4; ++r) { acc[g][r][0] = 0.f; acc[g][r][1] = 0.f; }

    #pragma unroll
    for (int k4i = 0; k4i < 8; ++k4i) {
      const int k4 = k4lo + k4i;
      float4 hv[4];
      #pragma unroll
      for (int r = 0; r < 4; ++r)
        hv[r] = *(const float4*)&hs[r][k4 * 4];   // LDS broadcast
      #pragma unroll
      for (int g = 0; g < 3; ++g) {
        Half8 w8 = *(const Half8*)(Wt + (long)(k4 * 3 + g) * 256 + d0);
        const float w0 = (float)w8.h[0], w1 = (float)w8.h[1],
                    w2 = (float)w8.h[2], w3 = (float)w8.h[3];
        const float v0 = (float)w8.h[4], v1 = (float)w8.h[5],
                    v2 = (float)w8.h[6], v3 = (float)w8.h[7];
        #pragma unroll
        for (int r = 0; r < 4; ++r) {
          float a0 = acc[g][r][0], a1 = acc[g][r][1];
          a0 = fmaf(hv[r].x, w0, a0); a0 = fmaf(hv[r].y, w1, a0);
          a0 = fmaf(hv[r].z, w2, a0); a0 = fmaf(hv[r].w, w3, a0);
          a1 = fmaf(hv[r].x, v0, a1); a1 = fmaf(hv[r].y, v1, a1);
          a1 = fmaf(hv[r].z, v2, a1); a1 = fmaf(hv[r].w, v3, a1);
          acc[g][r][0] = a0; acc[g][r][1] = a1;
        }
      }
    }
    #pragma unroll
    for (int g = 0; g < 3; ++g)
      #pragma unroll
      for (int r = 0; r < 4; ++r)
        *(float2*)&part[e][g * 4 + r][d0] =
            make_float2(acc[g][r][0], acc[g][r][1]);
    __syncthreads();   // partials visible; all eighths done reading hs

    // reduce 8 partials for (erow, ed), activate, update h
    {
      float sr = 0.f, sz = 0.f, sn = 0.f;
      #pragma unroll
      for (int ee = 0; ee < 8; ++ee) {
        sr += part[ee][0 * 4 + erow][ed];
        sz += part[ee][1 * 4 + erow][ed];
        sn += part[ee][2 * 4 + erow][ed];
      }
      float rg = 1.f / (1.f + __expf(-(gir + sr + bhr)));
      float zg = 1.f / (1.f + __expf(-(giz + sz + bhz)));
      float ng = tanhf(gin + rg * (sn + bhn));
      float hn = (1.f - zg) * ng + zg * hs[erow][ed];
      hs[erow][ed] = hn;   // unique owner of (erow, ed)
      if (store_all)
        h_out[((long)t * 1024 + b0 + erow) * 256 + ed] = hn;
    }
    __syncthreads();   // new h visible for step t+1
  }
  h_state[(long)(b0 + erow) * 256 + ed] = hs[erow][ed];
}

// ---------------------------------------------------------------------------
// Soft cluster assignment: q[b,k] ∝ 1/(1+||z_b - c_k||²)  (alpha=1), normalized.
// ---------------------------------------------------------------------------
__global__ __launch_bounds__(64)
void cluster_q(const float* __restrict__ zlat, const float* __restrict__ centers,
               float* __restrict__ q)
{
  __shared__ float red[64];
  __shared__ float qv[8];
  const int b = blockIdx.x;
  const int tid = threadIdx.x;
  const int k = tid >> 3, p = tid & 7;
  const float4* zp = (const float4*)(zlat + (long)b * 256 + p * 32);
  const float4* cp = (const float4*)(centers + (long)k * 256 + p * 32);
  float s = 0.f;
  #pragma unroll
  for (int i = 0; i < 8; ++i) {
    float4 zv = zp[i], cv = cp[i];
    float dx = zv.x - cv.x, dy = zv.y - cv.y;
    float dz = zv.z - cv.z, dw = zv.w - cv.w;
    s += dx*dx + dy*dy + dz*dz + dw*dw;
  }
  red[tid] = s;
  __syncthreads();
  if (tid < 8) {
    float d2 = 0.f;
    #pragma unroll
    for (int p2 = 0; p2 < 8; ++p2) d2 += red[tid * 8 + p2];
    qv[tid] = 1.f / (1.f + d2);
  }
  __syncthreads();
  if (tid < 8) {
    float ssum = 0.f;
    #pragma unroll
    for (int kk = 0; kk < 8; ++kk) ssum += qv[kk];
    q[(long)b * 8 + tid] = qv[tid] / ssum;
  }
}

// ---------------------------------------------------------------------------
// logits[b,k,c] = h2[b,k,:]·eW3[k,c,:] + eb3[k,c]; preds[b,c] = Σ_k q[b,k]*logits
// ---------------------------------------------------------------------------
__global__ __launch_bounds__(256)
void combine_preds(const float* __restrict__ h2, const float* __restrict__ eW3,
                   const float* __restrict__ eb3, const float* __restrict__ q,
                   float* __restrict__ out)
{
  __shared__ float p0[256], p1[256];
  __shared__ float lc[16];
  const int b = blockIdx.x;
  const int tid = threadIdx.x;
  const int k = tid >> 5, w = tid & 31;
  const float* h2p = h2 + (long)b * (8 * 256) + (long)k * 256 + w * 8;
  const float* w0  = eW3 + (long)k * 512 + w * 8;          // c=0
  const float* w1  = eW3 + (long)k * 512 + 256 + w * 8;    // c=1
  float c0 = 0.f, c1 = 0.f;
  #pragma unroll
  for (int i = 0; i < 8; ++i) {
    float hv = h2p[i];
    c0 = fmaf(hv, w0[i], c0);
    c1 = fmaf(hv, w1[i], c1);
  }
  p0[tid] = c0; p1[tid] = c1;
  __syncthreads();
  if (tid < 16) {
    int kk = tid >> 1, c = tid & 1;
    const float* pp = (c == 0) ? p0 : p1;
    float s = 0.f;
    for (int w2 = 0; w2 < 32; ++w2) s += pp[kk * 32 + w2];
    s += eb3[kk * 2 + c];
    lc[tid] = q[(long)b * 8 + kk] * s;
  }
  __syncthreads();
  if (tid < 2) {
    float s = 0.f;
    #pragma unroll
    for (int kk = 0; kk < 8; ++kk) s += lc[kk * 2 + tid];
    out[(long)b * 2 + tid] = s;
  }
}

// Zero-fill helper (avoid relying on memset semantics under graph capture)
__global__ __launch_bounds__(256)
void zero_fill(float* __restrict__ p, long n)
{
  long i = (long)blockIdx.x * 256 + threadIdx.x;
  if (i < n) p[i] = 0.f;
}

// ---------------------------------------------------------------------------
extern "C" void kernel_launch(void* const* d_in, const int* in_sizes, int n_in,
                              void* d_out, int out_size, void* d_ws, size_t ws_size,
                              hipStream_t stream)
{
  const float* x       = (const float*)d_in[0];
  const float* W_ih0   = (const float*)d_in[1];
  const float* W_hh0   = (const float*)d_in[2];
  const float* b_ih0   = (const float*)d_in[3];
  const float* b_hh0   = (const float*)d_in[4];
  const float* W_ih1   = (const float*)d_in[5];
  const float* W_hh1   = (const float*)d_in[6];
  const float* b_ih1   = (const float*)d_in[7];
  const float* b_hh1   = (const float*)d_in[8];
  const float* centers = (const float*)d_in[9];
  const float* eW1     = (const float*)d_in[10];
  const float* eb1     = (const float*)d_in[11];
  const float* eW2     = (const float*)d_in[12];
  const float* eb2     = (const float*)d_in[13];
  const float* eW3     = (const float*)d_in[14];
  const float* eb3     = (const float*)d_in[15];
  float* out = (float*)d_out;
  (void)in_sizes; (void)n_in; (void)out_size;

  // ---- workspace layout ----
  char* base = (char*)d_ws;
  size_t off = 0;
  auto alloc = [&](size_t nbytes) -> void* {
    void* p = base + off;
    off += (nbytes + 255) & ~(size_t)255;
    return p;
  };
  float* h0_state = (float*)alloc(1024ull * 256 * 4);
  float* h1_state = (float*)alloc(1024ull * 256 * 4);   // == z after layer 1
  float* qbuf     = (float*)alloc(1024ull * 8 * 4);
  float* h1buf    = (float*)alloc(1024ull * 8 * 512 * 4);
  float* h2buf    = (float*)alloc(1024ull * 8 * 256 * 4);
  Half4* Wt0      = (Half4*)alloc(768ull * 256 * 2);    // f16 transposed W_hh0
  Half4* Wt1      = (Half4*)alloc(768ull * 256 * 2);    // f16 transposed W_hh1
  const size_t fixed = off;

  // largest T-chunk that fits ws_size (deterministic given ws_size)
  int Tc = 2;
  const int cands[7] = {128, 64, 32, 16, 8, 4, 2};
  for (int ci = 0; ci < 7; ++ci) {
    size_t need = fixed + (size_t)cands[ci] * 1024 * (768 + 768 + 256) * 4 + 1024;
    if (need <= ws_size) { Tc = cands[ci]; break; }
  }
  float* gi0 = (float*)alloc((size_t)Tc * 1024 * 768 * 4);
  float* gi1 = (float*)alloc((size_t)Tc * 1024 * 768 * 4);
  float* h0c = (float*)alloc((size_t)Tc * 1024 * 256 * 4);

  // ---- zero recurrent states; transpose W_hh (once per call) ----
  {
    long n = 2L * 1024 * 256;   // h0_state + h1_state are contiguous
    zero_fill<<<dim3((unsigned)((n + 255) / 256)), 256, 0, stream>>>(h0_state, n);
    transpose_whh<<<768, 64, 0, stream>>>(W_hh0, Wt0);
    transpose_whh<<<768, 64, 0, stream>>>(W_hh1, Wt1);
  }

  // ---- 2-layer GRU, serial chunks (dual-stream pipelining thrashes L3) ----
  for (int t0 = 0; t0 < 128; t0 += Tc) {
    // gi0[tl,b,:] = x[b, t0+tl, :] @ W_ih0^T + b_ih0
    gemm_f32<0><<<dim3(6, Tc * 8, 1), 256, 0, stream>>>(
        x + (long)t0 * 128, W_ih0, b_ih0, gi0, 128,
        /*a_sT*/ 128, /*a_sB*/ 128L * 128, /*a_sZ*/ 0,
        /*w_sZ*/ 0, /*b_sZ*/ 0, /*c_row*/ 768, /*c_sZ*/ 0);
    gru_rec<<<256, 1024, 0, stream>>>(gi0, Wt0, b_hh0, h0_state, h0c, Tc, 1);

    // gi1[tl,b,:] = h0c[tl,b,:] @ W_ih1^T + b_ih1
    gemm_f32<0><<<dim3(6, Tc * 8, 1), 256, 0, stream>>>(
        h0c, W_ih1, b_ih1, gi1, 256,
        /*a_sT*/ 1024L * 256, /*a_sB*/ 256, /*a_sZ*/ 0,
        /*w_sZ*/ 0, /*b_sZ*/ 0, /*c_row*/ 768, /*c_sZ*/ 0);
    gru_rec<<<256, 1024, 0, stream>>>(gi1, Wt1, b_hh1, h1_state, nullptr, Tc, 0);
  }

  // ---- soft cluster assignment ----
  cluster_q<<<1024, 64, 0, stream>>>(h1_state, centers, qbuf);

  // ---- experts: h1 = relu(z @ eW1[k]^T + eb1[k]) ----
  gemm_f32<1><<<dim3(4, 8, 8), 256, 0, stream>>>(
      h1_state, eW1, eb1, h1buf, 256,
      /*a_sT*/ 0, /*a_sB*/ 256, /*a_sZ*/ 0,
      /*w_sZ*/ 512L * 256, /*b_sZ*/ 512, /*c_row*/ 8L * 512, /*c_sZ*/ 512);
  // h2 = relu(h1 @ eW2[k]^T + eb2[k])
  gemm_f32<1><<<dim3(2, 8, 8), 256, 0, stream>>>(
      h1buf, eW2, eb2, h2buf, 512,
      /*a_sT*/ 0, /*a_sB*/ 8L * 512, /*a_sZ*/ 512,
      /*w_sZ*/ 256L * 512, /*b_sZ*/ 256, /*c_row*/ 8L * 256, /*c_sZ*/ 256);

  // ---- logits + q-weighted combine ----
  combine_preds<<<1024, 256, 0, stream>>>(h2buf, eW3, eb3, qbuf, out);
}

// Round 10
// 3475.768 us; speedup vs baseline: 5.3948x; 5.1930x over previous
//
#include <hip/hip_runtime.h>
#include <hip/hip_fp16.h>
#include <math.h>

// Problem dims (fixed by reference)
//  B=1024, T=128, I=128, H=256, 3H=768, K=8, E1=512, E2=256, C=2

struct __align__(8)  Half4 { _Float16 x, y, z, w; };
struct __align__(16) Half8 { _Float16 h[8]; };

// ---------------------------------------------------------------------------
// fp32 GEMM, 128x128 tile, 256 threads, 8x8 per-thread microtile.
// ---------------------------------------------------------------------------
template<int ACT>
__global__ __launch_bounds__(256)
void gemm_f32(const float* __restrict__ A, const float* __restrict__ W,
              const float* __restrict__ bias, float* __restrict__ C,
              int K,
              long a_sT, long a_sB, long a_sZ,
              long w_sZ, long b_sZ, long c_row, long c_sZ)
{
  __shared__ alignas(16) float As[16][132];
  __shared__ alignas(16) float Ws[16][132];
  const int z = blockIdx.z;
  const float* Az = A + (long)z * a_sZ;
  const float* Wz = W + (long)z * w_sZ;
  const float* bz = bias + (long)z * b_sZ;
  const int m0 = blockIdx.y * 128;
  const int n0 = blockIdx.x * 128;
  const int tid = threadIdx.x;
  const int tx = tid & 15, ty = tid >> 4;

  const int row0 = tid >> 2, kq0 = tid & 3;
  const int row1 = (tid + 256) >> 2, kq1 = kq0;

  float acc[8][8];
  #pragma unroll
  for (int i = 0; i < 8; ++i)
    #pragma unroll
    for (int j = 0; j < 8; ++j) acc[i][j] = 0.f;

  const int ma0 = m0 + row0, ma1 = m0 + row1;
  const float* apr0 = Az + (long)(ma0 >> 10) * a_sT + (long)(ma0 & 1023) * a_sB + kq0 * 4;
  const float* apr1 = Az + (long)(ma1 >> 10) * a_sT + (long)(ma1 & 1023) * a_sB + kq1 * 4;
  const float* wpr0 = Wz + (long)(n0 + row0) * K + kq0 * 4;
  const float* wpr1 = Wz + (long)(n0 + row1) * K + kq1 * 4;

  float4 pa0 = *(const float4*)(apr0);
  float4 pa1 = *(const float4*)(apr1);
  float4 pw0 = *(const float4*)(wpr0);
  float4 pw1 = *(const float4*)(wpr1);

  for (int k0 = 0; k0 < K; k0 += 16) {
    As[kq0*4+0][row0] = pa0.x; As[kq0*4+1][row0] = pa0.y;
    As[kq0*4+2][row0] = pa0.z; As[kq0*4+3][row0] = pa0.w;
    As[kq1*4+0][row1] = pa1.x; As[kq1*4+1][row1] = pa1.y;
    As[kq1*4+2][row1] = pa1.z; As[kq1*4+3][row1] = pa1.w;
    Ws[kq0*4+0][row0] = pw0.x; Ws[kq0*4+1][row0] = pw0.y;
    Ws[kq0*4+2][row0] = pw0.z; Ws[kq0*4+3][row0] = pw0.w;
    Ws[kq1*4+0][row1] = pw1.x; Ws[kq1*4+1][row1] = pw1.y;
    Ws[kq1*4+2][row1] = pw1.z; Ws[kq1*4+3][row1] = pw1.w;
    __syncthreads();

    if (k0 + 16 < K) {
      pa0 = *(const float4*)(apr0 + k0 + 16);
      pa1 = *(const float4*)(apr1 + k0 + 16);
      pw0 = *(const float4*)(wpr0 + k0 + 16);
      pw1 = *(const float4*)(wpr1 + k0 + 16);
    }

    #pragma unroll
    for (int kk = 0; kk < 16; ++kk) {
      float4 a0 = *(const float4*)&As[kk][ty * 8];
      float4 a1 = *(const float4*)&As[kk][ty * 8 + 4];
      float4 b0 = *(const float4*)&Ws[kk][tx * 4];
      float4 b1 = *(const float4*)&Ws[kk][64 + tx * 4];
      float a[8] = {a0.x,a0.y,a0.z,a0.w,a1.x,a1.y,a1.z,a1.w};
      float b[8] = {b0.x,b0.y,b0.z,b0.w,b1.x,b1.y,b1.z,b1.w};
      #pragma unroll
      for (int i = 0; i < 8; ++i)
        #pragma unroll
        for (int j = 0; j < 8; ++j)
          acc[i][j] = fmaf(a[i], b[j], acc[i][j]);
    }
    __syncthreads();
  }

  float4 bv0 = *(const float4*)&bz[n0 + tx * 4];
  float4 bv1 = *(const float4*)&bz[n0 + 64 + tx * 4];
  #pragma unroll
  for (int i = 0; i < 8; ++i) {
    int m = m0 + ty * 8 + i;
    float* cp = C + (long)m * c_row + (long)z * c_sZ + n0;
    float4 o0, o1;
    o0.x = acc[i][0] + bv0.x; o0.y = acc[i][1] + bv0.y;
    o0.z = acc[i][2] + bv0.z; o0.w = acc[i][3] + bv0.w;
    o1.x = acc[i][4] + bv1.x; o1.y = acc[i][5] + bv1.y;
    o1.z = acc[i][6] + bv1.z; o1.w = acc[i][7] + bv1.w;
    if (ACT == 1) {
      o0.x = fmaxf(o0.x, 0.f); o0.y = fmaxf(o0.y, 0.f);
      o0.z = fmaxf(o0.z, 0.f); o0.w = fmaxf(o0.w, 0.f);
      o1.x = fmaxf(o1.x, 0.f); o1.y = fmaxf(o1.y, 0.f);
      o1.z = fmaxf(o1.z, 0.f); o1.w = fmaxf(o1.w, 0.f);
    }
    *(float4*)(cp + tx * 4) = o0;
    *(float4*)(cp + 64 + tx * 4) = o1;
  }
}

// ---------------------------------------------------------------------------
// One-time W_hh transpose + f16 convert into coalesced-by-d layout:
//   Wt[(k4*3 + gate)*256 + d] = Half4{ W[gate*256+d][4k4 .. 4k4+3] }
// ---------------------------------------------------------------------------
__global__ __launch_bounds__(64)
void transpose_whh(const float* __restrict__ W, Half4* __restrict__ Wt)
{
  const int row = blockIdx.x;          // 0..767 = gate*256 + d
  const int k4 = threadIdx.x;          // 0..63
  const int g = row >> 8, d = row & 255;
  float4 v = *(const float4*)(W + (long)row * 256 + k4 * 4);
  Half4 h;
  h.x = (_Float16)v.x; h.y = (_Float16)v.y;
  h.z = (_Float16)v.z; h.w = (_Float16)v.w;
  Wt[((long)k4 * 3 + g) * 256 + d] = h;
}

// ---------------------------------------------------------------------------
// GRU recurrence, 4-way split-K x 2-d-per-thread. 256 blocks x 512 THREADS
// (NOT 1024: this toolchain caps 16-wave workgroups at 64 VGPR -> rounds
// 8/9 spilled 5.6 GB to scratch. 512-thread blocks compile uncapped.)
// Block = 4 batch rows, 8 waves/CU.
// Thread (dp = tid&127, e = tid>>7 in 0..3): owns output dims d0=2dp, 2dp+1
// and k-range [64e, 64e+64) (16 k4 iters). Per k4: 3 coalesced 16B Half8 W
// loads, 4 LDS float4 h broadcasts, 96 fmaf. Total LDS b128 reads per CU
// per step HALVED vs round 5 (each hv feeds 2 output dims).
// Epilogue: thread handles (row = e, dims d0, d0+1): reduces 4 partials x 3
// gates x 2 dims, activations, h update. LDS: part 48 KB + hs 4 KB = 52 KB.
// ---------------------------------------------------------------------------
__global__ __launch_bounds__(512)
void gru_rec(const float* __restrict__ gi, const Half4* __restrict__ Wt,
             const float* __restrict__ b_hh, float* __restrict__ h_state,
             float* __restrict__ h_out, int Tc, int store_all)
{
  __shared__ alignas(16) float hs[4][256];
  __shared__ alignas(16) float part[4][12][256];   // 48 KB
  const int tid = threadIdx.x;
  const int dp = tid & 127;
  const int e  = tid >> 7;              // 0..3: k-quarter AND epilogue row
  const int b0 = blockIdx.x * 4;
  const int d0 = dp * 2;                // owned dims d0, d0+1

  *(float2*)&hs[e][d0] = *(const float2*)&h_state[(long)(b0 + e) * 256 + d0];
  __syncthreads();

  const float2 bhr = *(const float2*)&b_hh[d0];
  const float2 bhz = *(const float2*)&b_hh[256 + d0];
  const float2 bhn = *(const float2*)&b_hh[512 + d0];
  const int k4lo = e * 16;

  for (int t = 0; t < Tc; ++t) {
    // epilogue gi loads up front (nontemporal single-use stream);
    // latency overlaps the whole k-loop
    const float* gip = gi + ((long)t * 1024 + b0 + e) * 768;
    const float gir0 = __builtin_nontemporal_load(gip + d0);
    const float gir1 = __builtin_nontemporal_load(gip + d0 + 1);
    const float giz0 = __builtin_nontemporal_load(gip + 256 + d0);
    const float giz1 = __builtin_nontemporal_load(gip + 256 + d0 + 1);
    const float gin0 = __builtin_nontemporal_load(gip + 512 + d0);
    const float gin1 = __builtin_nontemporal_load(gip + 512 + d0 + 1);

    float acc[3][4][2];
    #pragma unroll
    for (int g = 0; g < 3; ++g)
      #pragma unroll
      for (int r = 0; r < 4; ++r) { acc[g][r][0] = 0.f; acc[g][r][1] = 0.f; }

    #pragma unroll 4
    for (int k4i = 0; k4i < 16; ++k4i) {
      const int k4 = k4lo + k4i;
      float4 hv[4];
      #pragma unroll
      for (int r = 0; r < 4; ++r)
        hv[r] = *(const float4*)&hs[r][k4 * 4];   // LDS broadcast
      #pragma unroll
      for (int g = 0; g < 3; ++g) {
        Half8 w8 = *(const Half8*)(Wt + (long)(k4 * 3 + g) * 256 + d0);
        const float w0 = (float)w8.h[0], w1 = (float)w8.h[1],
                    w2 = (float)w8.h[2], w3 = (float)w8.h[3];
        const float v0 = (float)w8.h[4], v1 = (float)w8.h[5],
                    v2 = (float)w8.h[6], v3 = (float)w8.h[7];
        #pragma unroll
        for (int r = 0; r < 4; ++r) {
          float a0 = acc[g][r][0], a1 = acc[g][r][1];
          a0 = fmaf(hv[r].x, w0, a0); a0 = fmaf(hv[r].y, w1, a0);
          a0 = fmaf(hv[r].z, w2, a0); a0 = fmaf(hv[r].w, w3, a0);
          a1 = fmaf(hv[r].x, v0, a1); a1 = fmaf(hv[r].y, v1, a1);
          a1 = fmaf(hv[r].z, v2, a1); a1 = fmaf(hv[r].w, v3, a1);
          acc[g][r][0] = a0; acc[g][r][1] = a1;
        }
      }
    }
    #pragma unroll
    for (int g = 0; g < 3; ++g)
      #pragma unroll
      for (int r = 0; r < 4; ++r)
        *(float2*)&part[e][g * 4 + r][d0] =
            make_float2(acc[g][r][0], acc[g][r][1]);
    __syncthreads();   // partials visible; all quarters done reading hs

    // reduce 4 partials for (row e, dims d0, d0+1), activate, update h
    {
      float sr0 = 0.f, sr1 = 0.f, sz0 = 0.f, sz1 = 0.f, sn0 = 0.f, sn1 = 0.f;
      #pragma unroll
      for (int ee = 0; ee < 4; ++ee) {
        float2 pr = *(const float2*)&part[ee][0 * 4 + e][d0];
        float2 pz = *(const float2*)&part[ee][1 * 4 + e][d0];
        float2 pn = *(const float2*)&part[ee][2 * 4 + e][d0];
        sr0 += pr.x; sr1 += pr.y;
        sz0 += pz.x; sz1 += pz.y;
        sn0 += pn.x; sn1 += pn.y;
      }
      float rg0 = 1.f / (1.f + __expf(-(gir0 + sr0 + bhr.x)));
      float rg1 = 1.f / (1.f + __expf(-(gir1 + sr1 + bhr.y)));
      float zg0 = 1.f / (1.f + __expf(-(giz0 + sz0 + bhz.x)));
      float zg1 = 1.f / (1.f + __expf(-(giz1 + sz1 + bhz.y)));
      float ng0 = tanhf(gin0 + rg0 * (sn0 + bhn.x));
      float ng1 = tanhf(gin1 + rg1 * (sn1 + bhn.y));
      float2 hold = *(const float2*)&hs[e][d0];
      float hn0 = (1.f - zg0) * ng0 + zg0 * hold.x;
      float hn1 = (1.f - zg1) * ng1 + zg1 * hold.y;
      *(float2*)&hs[e][d0] = make_float2(hn0, hn1);   // unique owner
      if (store_all)
        *(float2*)&h_out[((long)t * 1024 + b0 + e) * 256 + d0] =
            make_float2(hn0, hn1);
    }
    __syncthreads();   // new h visible for step t+1
  }
  *(float2*)&h_state[(long)(b0 + e) * 256 + d0] = *(const float2*)&hs[e][d0];
}

// ---------------------------------------------------------------------------
// Soft cluster assignment: q[b,k] ∝ 1/(1+||z_b - c_k||²)  (alpha=1), normalized.
// ---------------------------------------------------------------------------
__global__ __launch_bounds__(64)
void cluster_q(const float* __restrict__ zlat, const float* __restrict__ centers,
               float* __restrict__ q)
{
  __shared__ float red[64];
  __shared__ float qv[8];
  const int b = blockIdx.x;
  const int tid = threadIdx.x;
  const int k = tid >> 3, p = tid & 7;
  const float4* zp = (const float4*)(zlat + (long)b * 256 + p * 32);
  const float4* cp = (const float4*)(centers + (long)k * 256 + p * 32);
  float s = 0.f;
  #pragma unroll
  for (int i = 0; i < 8; ++i) {
    float4 zv = zp[i], cv = cp[i];
    float dx = zv.x - cv.x, dy = zv.y - cv.y;
    float dz = zv.z - cv.z, dw = zv.w - cv.w;
    s += dx*dx + dy*dy + dz*dz + dw*dw;
  }
  red[tid] = s;
  __syncthreads();
  if (tid < 8) {
    float d2 = 0.f;
    #pragma unroll
    for (int p2 = 0; p2 < 8; ++p2) d2 += red[tid * 8 + p2];
    qv[tid] = 1.f / (1.f + d2);
  }
  __syncthreads();
  if (tid < 8) {
    float ssum = 0.f;
    #pragma unroll
    for (int kk = 0; kk < 8; ++kk) ssum += qv[kk];
    q[(long)b * 8 + tid] = qv[tid] / ssum;
  }
}

// ---------------------------------------------------------------------------
// logits[b,k,c] = h2[b,k,:]·eW3[k,c,:] + eb3[k,c]; preds[b,c] = Σ_k q[b,k]*logits
// ---------------------------------------------------------------------------
__global__ __launch_bounds__(256)
void combine_preds(const float* __restrict__ h2, const float* __restrict__ eW3,
                   const float* __restrict__ eb3, const float* __restrict__ q,
                   float* __restrict__ out)
{
  __shared__ float p0[256], p1[256];
  __shared__ float lc[16];
  const int b = blockIdx.x;
  const int tid = threadIdx.x;
  const int k = tid >> 5, w = tid & 31;
  const float* h2p = h2 + (long)b * (8 * 256) + (long)k * 256 + w * 8;
  const float* w0  = eW3 + (long)k * 512 + w * 8;          // c=0
  const float* w1  = eW3 + (long)k * 512 + 256 + w * 8;    // c=1
  float c0 = 0.f, c1 = 0.f;
  #pragma unroll
  for (int i = 0; i < 8; ++i) {
    float hv = h2p[i];
    c0 = fmaf(hv, w0[i], c0);
    c1 = fmaf(hv, w1[i], c1);
  }
  p0[tid] = c0; p1[tid] = c1;
  __syncthreads();
  if (tid < 16) {
    int kk = tid >> 1, c = tid & 1;
    const float* pp = (c == 0) ? p0 : p1;
    float s = 0.f;
    for (int w2 = 0; w2 < 32; ++w2) s += pp[kk * 32 + w2];
    s += eb3[kk * 2 + c];
    lc[tid] = q[(long)b * 8 + kk] * s;
  }
  __syncthreads();
  if (tid < 2) {
    float s = 0.f;
    #pragma unroll
    for (int kk = 0; kk < 8; ++kk) s += lc[kk * 2 + tid];
    out[(long)b * 2 + tid] = s;
  }
}

// Zero-fill helper (avoid relying on memset semantics under graph capture)
__global__ __launch_bounds__(256)
void zero_fill(float* __restrict__ p, long n)
{
  long i = (long)blockIdx.x * 256 + threadIdx.x;
  if (i < n) p[i] = 0.f;
}

// ---------------------------------------------------------------------------
extern "C" void kernel_launch(void* const* d_in, const int* in_sizes, int n_in,
                              void* d_out, int out_size, void* d_ws, size_t ws_size,
                              hipStream_t stream)
{
  const float* x       = (const float*)d_in[0];
  const float* W_ih0   = (const float*)d_in[1];
  const float* W_hh0   = (const float*)d_in[2];
  const float* b_ih0   = (const float*)d_in[3];
  const float* b_hh0   = (const float*)d_in[4];
  const float* W_ih1   = (const float*)d_in[5];
  const float* W_hh1   = (const float*)d_in[6];
  const float* b_ih1   = (const float*)d_in[7];
  const float* b_hh1   = (const float*)d_in[8];
  const float* centers = (const float*)d_in[9];
  const float* eW1     = (const float*)d_in[10];
  const float* eb1     = (const float*)d_in[11];
  const float* eW2     = (const float*)d_in[12];
  const float* eb2     = (const float*)d_in[13];
  const float* eW3     = (const float*)d_in[14];
  const float* eb3     = (const float*)d_in[15];
  float* out = (float*)d_out;
  (void)in_sizes; (void)n_in; (void)out_size;

  // ---- workspace layout ----
  char* base = (char*)d_ws;
  size_t off = 0;
  auto alloc = [&](size_t nbytes) -> void* {
    void* p = base + off;
    off += (nbytes + 255) & ~(size_t)255;
    return p;
  };
  float* h0_state = (float*)alloc(1024ull * 256 * 4);
  float* h1_state = (float*)alloc(1024ull * 256 * 4);   // == z after layer 1
  float* qbuf     = (float*)alloc(1024ull * 8 * 4);
  float* h1buf    = (float*)alloc(1024ull * 8 * 512 * 4);
  float* h2buf    = (float*)alloc(1024ull * 8 * 256 * 4);
  Half4* Wt0      = (Half4*)alloc(768ull * 256 * 2);    // f16 transposed W_hh0
  Half4* Wt1      = (Half4*)alloc(768ull * 256 * 2);    // f16 transposed W_hh1
  const size_t fixed = off;

  // largest T-chunk that fits ws_size (deterministic given ws_size)
  int Tc = 2;
  const int cands[7] = {128, 64, 32, 16, 8, 4, 2};
  for (int ci = 0; ci < 7; ++ci) {
    size_t need = fixed + (size_t)cands[ci] * 1024 * (768 + 768 + 256) * 4 + 1024;
    if (need <= ws_size) { Tc = cands[ci]; break; }
  }
  float* gi0 = (float*)alloc((size_t)Tc * 1024 * 768 * 4);
  float* gi1 = (float*)alloc((size_t)Tc * 1024 * 768 * 4);
  float* h0c = (float*)alloc((size_t)Tc * 1024 * 256 * 4);

  // ---- zero recurrent states; transpose W_hh (once per call) ----
  {
    long n = 2L * 1024 * 256;   // h0_state + h1_state are contiguous
    zero_fill<<<dim3((unsigned)((n + 255) / 256)), 256, 0, stream>>>(h0_state, n);
    transpose_whh<<<768, 64, 0, stream>>>(W_hh0, Wt0);
    transpose_whh<<<768, 64, 0, stream>>>(W_hh1, Wt1);
  }

  // ---- 2-layer GRU, serial chunks (dual-stream pipelining thrashes L3) ----
  for (int t0 = 0; t0 < 128; t0 += Tc) {
    // gi0[tl,b,:] = x[b, t0+tl, :] @ W_ih0^T + b_ih0
    gemm_f32<0><<<dim3(6, Tc * 8, 1), 256, 0, stream>>>(
        x + (long)t0 * 128, W_ih0, b_ih0, gi0, 128,
        /*a_sT*/ 128, /*a_sB*/ 128L * 128, /*a_sZ*/ 0,
        /*w_sZ*/ 0, /*b_sZ*/ 0, /*c_row*/ 768, /*c_sZ*/ 0);
    gru_rec<<<256, 512, 0, stream>>>(gi0, Wt0, b_hh0, h0_state, h0c, Tc, 1);

    // gi1[tl,b,:] = h0c[tl,b,:] @ W_ih1^T + b_ih1
    gemm_f32<0><<<dim3(6, Tc * 8, 1), 256, 0, stream>>>(
        h0c, W_ih1, b_ih1, gi1, 256,
        /*a_sT*/ 1024L * 256, /*a_sB*/ 256, /*a_sZ*/ 0,
        /*w_sZ*/ 0, /*b_sZ*/ 0, /*c_row*/ 768, /*c_sZ*/ 0);
    gru_rec<<<256, 512, 0, stream>>>(gi1, Wt1, b_hh1, h1_state, nullptr, Tc, 0);
  }

  // ---- soft cluster assignment ----
  cluster_q<<<1024, 64, 0, stream>>>(h1_state, centers, qbuf);

  // ---- experts: h1 = relu(z @ eW1[k]^T + eb1[k]) ----
  gemm_f32<1><<<dim3(4, 8, 8), 256, 0, stream>>>(
      h1_state, eW1, eb1, h1buf, 256,
      /*a_sT*/ 0, /*a_sB*/ 256, /*a_sZ*/ 0,
      /*w_sZ*/ 512L * 256, /*b_sZ*/ 512, /*c_row*/ 8L * 512, /*c_sZ*/ 512);
  // h2 = relu(h1 @ eW2[k]^T + eb2[k])
  gemm_f32<1><<<dim3(2, 8, 8), 256, 0, stream>>>(
      h1buf, eW2, eb2, h2buf, 512,
      /*a_sT*/ 0, /*a_sB*/ 8L * 512, /*a_sZ*/ 512,
      /*w_sZ*/ 256L * 512, /*b_sZ*/ 256, /*c_row*/ 8L * 256, /*c_sZ*/ 256);

  // ---- logits + q-weighted combine ----
  combine_preds<<<1024, 256, 0, stream>>>(h2buf, eW3, eb3, qbuf, out);
}